// Round 2
// baseline (190.149 us; speedup 1.0000x reference)
//
#include <hip/hip_runtime.h>

// InnerProduct: lp[r,p] = sum_f w[p,f]^2 * sum_e x[r,f,e]^2
// R=32768, F=64, E=16, P=10. Memory-bound: one pass over x (128 MiB).
//
// Design: thread-per-(row,f). Each thread reads its f-chunk (16 floats = 4
// float4 = 64 B contiguous) with NO cross-lane dependencies, giving 16
// independent loads (1 KB) in flight per thread. Block = 16-row tile:
// phase A writes xsq[16][64] to LDS, one barrier, phase B does the tiny
// [16x64]x[64x10] contraction from LDS and writes 640 contiguous bytes.
constexpr int F = 64;
constexpr int E = 16;
constexpr int P = 10;
constexpr int TILE_ROWS = 16;
constexpr int LDS_PITCH = 68;  // pad 64->68: keeps 16B alignment for b128,
                               // phase-A write conflicts 2-way (free, m136)

__global__ __launch_bounds__(256, 4) void ip_kernel(const float* __restrict__ x,
                                                    const float* __restrict__ w,
                                                    float* __restrict__ out,
                                                    int n_tiles) {
    __shared__ float xsq_s[TILE_ROWS][LDS_PITCH];
    __shared__ float wsq_s[P][LDS_PITCH];

    const int tid = threadIdx.x;
    const int f = tid & 63;
    const int r0 = tid >> 6;  // 0..3

    // Squared weights into LDS once per block (640 values, 256 threads).
    for (int idx = tid; idx < P * F; idx += 256) {
        const float wv = w[idx];
        wsq_s[idx >> 6][idx & 63] = wv * wv;  // idx = p*64 + f
    }
    // (first __syncthreads below covers this before any phase-B read)

    for (int tile = blockIdx.x; tile < n_tiles; tile += gridDim.x) {
        const float* xt = x + (size_t)tile * (TILE_ROWS * F * E);

        // ---- Phase A: issue all 16 loads, then square-reduce per thread ----
        float4 v[4][4];
#pragma unroll
        for (int k = 0; k < 4; ++k) {
            const int r = r0 + 4 * k;
            const float4* src = (const float4*)(xt + ((size_t)r * F + f) * E);
#pragma unroll
            for (int s = 0; s < 4; ++s) v[k][s] = src[s];
        }
#pragma unroll
        for (int k = 0; k < 4; ++k) {
            float s = 0.0f;
#pragma unroll
            for (int seg = 0; seg < 4; ++seg) {
                const float4 t = v[k][seg];
                s += t.x * t.x + t.y * t.y + t.z * t.z + t.w * t.w;
            }
            xsq_s[r0 + 4 * k][f] = s;
        }
        __syncthreads();

        // ---- Phase B: lp[r][p] = sum_f wsq[p][f] * xsq[r][f] ----
        if (tid < TILE_ROWS * P) {
            const int r = tid / P;   // 0..15
            const int p = tid % P;   // 0..9
            float acc = 0.0f;
#pragma unroll
            for (int f4 = 0; f4 < F; f4 += 4) {
                const float4 xa = *(const float4*)&xsq_s[r][f4];
                const float4 wa = *(const float4*)&wsq_s[p][f4];
                acc += xa.x * wa.x + xa.y * wa.y + xa.z * wa.z + xa.w * wa.w;
            }
            // lane j writes word j of the tile's 640 B output: contiguous.
            out[(size_t)tile * (TILE_ROWS * P) + tid] = acc;
        }
        __syncthreads();  // xsq_s reused next tile
    }
}

extern "C" void kernel_launch(void* const* d_in, const int* in_sizes, int n_in,
                              void* d_out, int out_size, void* d_ws, size_t ws_size,
                              hipStream_t stream) {
    const float* x = (const float*)d_in[0];
    const float* w = (const float*)d_in[1];
    float* out = (float*)d_out;
    const int rows = in_sizes[0] / (F * E);   // 32768
    const int n_tiles = rows / TILE_ROWS;     // 2048

    dim3 grid(2048), block(256);
    hipLaunchKernelGGL(ip_kernel, grid, block, 0, stream, x, w, out, n_tiles);
}